// Round 1
// baseline (178.291 us; speedup 1.0000x reference)
//
#include <hip/hip_runtime.h>
#include <hip/hip_bf16.h>

// DynamicConv1D: out[b,t,f] = sum_{k,d} xp[b,t+k,d] * kernels[b,t,k,f]
// Factorizes: out[b,t,f] = sum_k S[b,t+k-1] * kernels[b,t,k,f],
// where S[b,u] = sum_d x[b,u,d], S out-of-range = 0.
// B=8, T=2048, D=512, K=3, F=512. All fp32. Memory-bound (~160 MiB traffic).

#define B_ 8
#define T_ 2048
#define D_ 512
#define F_ 512

// Kernel 1: row sums. One wave (64 lanes) per (b,t) row; 4 waves per block.
__global__ __launch_bounds__(256) void rowsum_kernel(
    const float* __restrict__ x, float* __restrict__ S) {
    const int row  = blockIdx.x * 4 + (threadIdx.x >> 6);   // 0 .. B*T-1
    const int lane = threadIdx.x & 63;
    const float4* xr = (const float4*)(x + (size_t)row * D_);
    // D/4 = 128 float4 per row; 64 lanes -> 2 each (coalesced, 16B/lane)
    float4 a = xr[lane];
    float4 b = xr[lane + 64];
    float s = (a.x + a.y) + (a.z + a.w) + (b.x + b.y) + (b.z + b.w);
    // wave-64 shuffle reduction
    #pragma unroll
    for (int off = 32; off > 0; off >>= 1)
        s += __shfl_down(s, off, 64);
    if (lane == 0) S[row] = s;
}

// Kernel 2: 3-tap combine. One 128-thread block per (b,t); each thread owns
// one float4 of the F dimension (128 * 4 = 512 = F).
__global__ __launch_bounds__(128) void conv_kernel(
    const float* __restrict__ kern, const float* __restrict__ S,
    float* __restrict__ out) {
    const int bt = blockIdx.x;          // 0 .. B*T-1
    const int t  = bt & (T_ - 1);       // T is a power of two

    // Wave-uniform boundary handling (t uniform per block)
    const float s0 = (t > 0)      ? S[bt - 1] : 0.0f;
    const float s1 = S[bt];
    const float s2 = (t < T_ - 1) ? S[bt + 1] : 0.0f;

    const float4* kr = (const float4*)(kern + (size_t)bt * 3 * F_);
    const int i = threadIdx.x;
    float4 k0 = kr[i];                  // k = 0 plane
    float4 k1 = kr[i + F_ / 4];         // k = 1 plane
    float4 k2 = kr[i + 2 * (F_ / 4)];   // k = 2 plane

    float4 o;
    o.x = s0 * k0.x + s1 * k1.x + s2 * k2.x;
    o.y = s0 * k0.y + s1 * k1.y + s2 * k2.y;
    o.z = s0 * k0.z + s1 * k1.z + s2 * k2.z;
    o.w = s0 * k0.w + s1 * k1.w + s2 * k2.w;

    ((float4*)(out + (size_t)bt * F_))[i] = o;
}

extern "C" void kernel_launch(void* const* d_in, const int* in_sizes, int n_in,
                              void* d_out, int out_size, void* d_ws, size_t ws_size,
                              hipStream_t stream) {
    const float* x    = (const float*)d_in[0];   // [B, T, D]
    const float* kern = (const float*)d_in[1];   // [B, T, K, F]
    float* out = (float*)d_out;                  // [B, T, F]
    float* S   = (float*)d_ws;                   // [B*T] row sums (64 KiB)

    const int rows = B_ * T_;                    // 16384
    rowsum_kernel<<<rows / 4, 256, 0, stream>>>(x, S);
    conv_kernel<<<rows, 128, 0, stream>>>(kern, S, out);
}